// Round 10
// baseline (843.314 us; speedup 1.0000x reference)
//
#include <hip/hip_runtime.h>
#include <hip/hip_bf16.h>
#include <math.h>

#define D 256
#define EPS 1e-5f
#define SCAN_NB 256

typedef _Float16 f16;
typedef _Float16 f16x4 __attribute__((ext_vector_type(4)));
typedef _Float16 f16x8 __attribute__((ext_vector_type(8)));
typedef float f32x4v __attribute__((ext_vector_type(4)));

// ---------------------------------------------------------------- CSR build
__global__ void k_count(const int* __restrict__ dst, int* __restrict__ cnt, int E) {
    int e = blockIdx.x * blockDim.x + threadIdx.x;
    if (e < E) atomicAdd(&cnt[dst[e]], 1);
}

__global__ void k_scan_part(const int* __restrict__ cnt, int* __restrict__ row_ptr,
                            int* __restrict__ partial, int N, int C) {
    __shared__ int sdata[256];
    int b = blockIdx.x, t = threadIdx.x;
    int base = b * C;
    int end = base + C; if (end > N) end = N;
    int running = 0;
    for (int ts = base; ts < end; ts += 256) {
        int idx = ts + t;
        int val = (idx < end) ? cnt[idx] : 0;
        sdata[t] = val;
        __syncthreads();
        for (int s = 1; s < 256; s <<= 1) {
            int v = (t >= s) ? sdata[t - s] : 0;
            __syncthreads();
            sdata[t] += v;
            __syncthreads();
        }
        if (idx < end) row_ptr[idx] = running + sdata[t] - val;
        running += sdata[255];
        __syncthreads();
    }
    if (t == 0) partial[b] = running;
}

__global__ void k_scan_off(int* __restrict__ partial) {
    __shared__ int sdata[256];
    int t = threadIdx.x;
    int val = partial[t];
    sdata[t] = val;
    __syncthreads();
    for (int s = 1; s < 256; s <<= 1) {
        int v = (t >= s) ? sdata[t - s] : 0;
        __syncthreads();
        sdata[t] += v;
        __syncthreads();
    }
    partial[t] = sdata[t] - val;
}

// add block offsets, emit cursor, close row_ptr; dinv folded in (reads cnt)
__global__ void k_scan_add(int* __restrict__ row_ptr, int* __restrict__ cursor,
                           const int* __restrict__ partial, const int* __restrict__ cnt,
                           float* __restrict__ dinv, int N, int C, int E) {
    int i = blockIdx.x * 256 + threadIdx.x;
    if (i < N) {
        int v = row_ptr[i] + partial[i / C];
        row_ptr[i] = v;
        cursor[i]  = v;
        dinv[i] = rsqrtf(1.0f + (float)cnt[i]);
    }
    if (i == N) row_ptr[N] = E;
}

__global__ void k_fill(const int* __restrict__ src, const int* __restrict__ dst,
                       const float* __restrict__ dinv, int* __restrict__ cursor,
                       int* __restrict__ col, float* __restrict__ coef, int E) {
    int e = blockIdx.x * blockDim.x + threadIdx.x;
    if (e >= E) return;
    int s = src[e], t = dst[e];
    int slot = atomicAdd(&cursor[t], 1);
    col[slot]  = s;
    coef[slot] = dinv[s] * dinv[t];
}

// ---------------------------------------------------------------- casts / weight prep
__global__ void k_cast(const float* __restrict__ in, f16* __restrict__ o, int n4) {
    int i = blockIdx.x * 256 + threadIdx.x;
    if (i >= n4) return;
    float4 v = ((const float4*)in)[i];
    f16x4 h = {(f16)v.x, (f16)v.y, (f16)v.z, (f16)v.w};
    ((f16x4*)o)[i] = h;
}

// Wt[d][k] = (f16) W[k][d]; W is [K][256]. Block 0 also zeroes the BN-stat accumulators.
__global__ void k_prep_w(const float* __restrict__ W, f16* __restrict__ Wt, int K,
                         float* __restrict__ sums, float* __restrict__ sumsq) {
    int idx = blockIdx.x * 256 + threadIdx.x;
    if (blockIdx.x == 0) {
        sums[threadIdx.x]  = 0.f;
        sumsq[threadIdx.x] = 0.f;
    }
    if (idx >= K * 256) return;
    int k = idx >> 8, d = idx & 255;
    Wt[(size_t)d * K + k] = (f16)W[idx];
}

// ---------------------------------------------------------------- MFMA GEMM (m93 pattern)
// 128x128 tile, 4 waves 2x2, each wave 4x4 grid of 16x16x32 MFMAs.
#define KSTEP 32
#define ATS 40
__global__ __launch_bounds__(256)
void k_gemm(const f16* __restrict__ A, const f16* __restrict__ Wt,
            f16* __restrict__ outh, int N, int K,
            float* __restrict__ sums, float* __restrict__ sumsq) {
    __shared__ __align__(16) f16 As[128 * ATS];
    __shared__ __align__(16) f16 Bs[128 * ATS];
    const int r0 = blockIdx.x * 128;
    const int c0 = blockIdx.y * 128;
    const int t = threadIdx.x;
    const int lane = t & 63, wave = t >> 6;
    const int wr = wave >> 1, wc = wave & 1;
    const int quad = lane >> 4, m = lane & 15;

    f32x4v acc[4][4];
#pragma unroll
    for (int i = 0; i < 4; ++i)
#pragma unroll
        for (int j = 0; j < 4; ++j) acc[i][j] = {0.f, 0.f, 0.f, 0.f};

    const int sr = t >> 1;
    const int sc8 = (t & 1) * 16;

    for (int k0 = 0; k0 < K; k0 += KSTEP) {
        int gr = r0 + sr;
        uint4 a0 = make_uint4(0u,0u,0u,0u), a1 = make_uint4(0u,0u,0u,0u);
        if (gr < N) {
            const f16* ap = A + (size_t)gr * K + k0 + sc8;
            a0 = *(const uint4*)ap;
            a1 = *(const uint4*)(ap + 8);
        }
        *(uint4*)(As + sr * ATS + sc8)     = a0;
        *(uint4*)(As + sr * ATS + sc8 + 8) = a1;
        const f16* bp = Wt + (size_t)(c0 + sr) * K + k0 + sc8;
        *(uint4*)(Bs + sr * ATS + sc8)     = *(const uint4*)bp;
        *(uint4*)(Bs + sr * ATS + sc8 + 8) = *(const uint4*)(bp + 8);
        __syncthreads();

        f16x8 af[4], bf[4];
#pragma unroll
        for (int i = 0; i < 4; ++i)
            af[i] = *(const f16x8*)(As + (wr * 64 + i * 16 + m) * ATS + quad * 8);
#pragma unroll
        for (int j = 0; j < 4; ++j)
            bf[j] = *(const f16x8*)(Bs + (wc * 64 + j * 16 + m) * ATS + quad * 8);
#pragma unroll
        for (int i = 0; i < 4; ++i)
#pragma unroll
            for (int j = 0; j < 4; ++j)
                acc[i][j] = __builtin_amdgcn_mfma_f32_16x16x32_f16(af[i], bf[j], acc[i][j], 0, 0, 0);
        __syncthreads();
    }

#pragma unroll
    for (int i = 0; i < 4; ++i) {
#pragma unroll
        for (int r = 0; r < 4; ++r) {
            int row = r0 + wr * 64 + i * 16 + quad * 4 + r;
            if (row < N) {
#pragma unroll
                for (int j = 0; j < 4; ++j) {
                    int colm = c0 + wc * 64 + j * 16 + m;
                    outh[(size_t)row * D + colm] = (f16)acc[i][j][r];
                }
            }
        }
    }

    if (sums) {
        __shared__ float cs[128], css[128];
        if (t < 128) { cs[t] = 0.f; css[t] = 0.f; }
        __syncthreads();
#pragma unroll
        for (int j = 0; j < 4; ++j) {
            int f = wc * 64 + j * 16 + m;
            float s = 0.f, q = 0.f;
#pragma unroll
            for (int i = 0; i < 4; ++i)
#pragma unroll
                for (int r = 0; r < 4; ++r) {
                    float v = acc[i][j][r];
                    s += v; q += v * v;
                }
            atomicAdd(&cs[f], s);
            atomicAdd(&css[f], q);
        }
        __syncthreads();
        if (t < 128) {
            atomicAdd(&sums[c0 + t], cs[t]);
            atomicAdd(&sumsq[c0 + t], css[t]);
        }
    }
}

// ---------------------------------------------------------------- gather, 256-dim rows (layers 1-3)
// wave-per-node, f16x4/lane; SOFTWARE-PIPELINED: cols prefetched 2 chunks ahead,
// rows 1 chunk ahead -> loads stay in flight through the FMA phase.
__global__ __launch_bounds__(256, 4)
void k_gather(const int* __restrict__ row_ptr, const int* __restrict__ col,
              const float* __restrict__ coef, const f16* __restrict__ hw,
              const float* __restrict__ dinv,
              f16* __restrict__ out, float* __restrict__ sums,
              float* __restrict__ sumsq, int N) {
    const int lane = threadIdx.x & 63;
    const int wave = threadIdx.x >> 6;
    const f16x4* __restrict__ hw4 = (const f16x4*)hw;
    f16x4* __restrict__ out4 = (f16x4*)out;

    float4 s4  = make_float4(0.f, 0.f, 0.f, 0.f);
    float4 ss4 = make_float4(0.f, 0.f, 0.f, 0.f);

    int wslot  = blockIdx.x * 4 + wave;
    int wtotal = gridDim.x * 4;
    for (int i = wslot; i < N; i += wtotal) {
        int lo = row_ptr[i];
        int hi = row_ptr[i + 1];
        float di = dinv[i];
        float dd = di * di;
        f16x4 hv = hw4[(size_t)i * 64 + lane];
        float4 acc;
        acc.x = (float)hv[0] * dd;
        acc.y = (float)hv[1] * dd;
        acc.z = (float)hv[2] * dd;
        acc.w = (float)hv[3] * dd;

        if (lo < hi) {
            int nd1[8]; float cf0[8], cf1[8]; f16x4 r0[8];
            // cols chunk 0 + issue rows chunk 0
            {
                int nd0[8];
#pragma unroll
                for (int j = 0; j < 8; ++j) {
                    int ej = lo + j;
                    int ec = (ej < hi) ? ej : lo;
                    nd0[j] = col[ec];
                    cf0[j] = (ej < hi) ? coef[ec] : 0.f;
                }
#pragma unroll
                for (int j = 0; j < 8; ++j) r0[j] = hw4[(size_t)nd0[j] * 64 + lane];
            }
            // cols chunk 1
#pragma unroll
            for (int j = 0; j < 8; ++j) {
                int ej = lo + 8 + j;
                int ec = (ej < hi) ? ej : lo;
                nd1[j] = col[ec];
                cf1[j] = (ej < hi) ? coef[ec] : 0.f;
            }

            for (int e = lo; e < hi; e += 8) {
                // prefetch cols chunk k+2
                int nd2[8]; float cf2[8];
#pragma unroll
                for (int j = 0; j < 8; ++j) {
                    int ej = e + 16 + j;
                    int ec = (ej < hi) ? ej : lo;
                    nd2[j] = col[ec];
                    cf2[j] = (ej < hi) ? coef[ec] : 0.f;
                }
                // issue rows chunk k+1
                f16x4 r1[8];
#pragma unroll
                for (int j = 0; j < 8; ++j) r1[j] = hw4[(size_t)nd1[j] * 64 + lane];
                // FMA chunk k
#pragma unroll
                for (int j = 0; j < 8; ++j) {
                    acc.x = fmaf((float)r0[j][0], cf0[j], acc.x);
                    acc.y = fmaf((float)r0[j][1], cf0[j], acc.y);
                    acc.z = fmaf((float)r0[j][2], cf0[j], acc.z);
                    acc.w = fmaf((float)r0[j][3], cf0[j], acc.w);
                }
                // shift pipeline
#pragma unroll
                for (int j = 0; j < 8; ++j) {
                    r0[j] = r1[j]; cf0[j] = cf1[j];
                    nd1[j] = nd2[j]; cf1[j] = cf2[j];
                }
            }
        }

        f16x4 o = {(f16)acc.x, (f16)acc.y, (f16)acc.z, (f16)acc.w};
        out4[(size_t)i * 64 + lane] = o;
        s4.x += acc.x; s4.y += acc.y; s4.z += acc.z; s4.w += acc.w;
        ss4.x += acc.x * acc.x; ss4.y += acc.y * acc.y;
        ss4.z += acc.z * acc.z; ss4.w += acc.w * acc.w;
    }

    __shared__ float rs[4][256];
    __shared__ float rss[4][256];
    int f = lane * 4;
    rs[wave][f + 0] = s4.x;  rs[wave][f + 1] = s4.y;
    rs[wave][f + 2] = s4.z;  rs[wave][f + 3] = s4.w;
    rss[wave][f + 0] = ss4.x; rss[wave][f + 1] = ss4.y;
    rss[wave][f + 2] = ss4.z; rss[wave][f + 3] = ss4.w;
    __syncthreads();
    int t = threadIdx.x;
    float rsum  = rs[0][t] + rs[1][t] + rs[2][t] + rs[3][t];
    float rsum2 = rss[0][t] + rss[1][t] + rss[2][t] + rss[3][t];
    atomicAdd(&sums[t], rsum);
    atomicAdd(&sumsq[t], rsum2);
}

// ---------------------------------------------------------------- gather, 64-dim rows (layer 0), pipelined
__global__ __launch_bounds__(256, 4)
void k_gather64(const int* __restrict__ row_ptr, const int* __restrict__ col,
                const float* __restrict__ coef, const f16* __restrict__ xh,
                const float* __restrict__ dinv, f16* __restrict__ aggx, int N) {
    const int lane = threadIdx.x & 63;
    const int wave = threadIdx.x >> 6;

    int wslot  = blockIdx.x * 4 + wave;
    int wtotal = gridDim.x * 4;
    for (int i = wslot; i < N; i += wtotal) {
        int lo = row_ptr[i];
        int hi = row_ptr[i + 1];
        float di = dinv[i];
        float acc = (float)xh[(size_t)i * 64 + lane] * (di * di);

        if (lo < hi) {
            int nd1[8]; float cf0[8], cf1[8]; float r0[8];
            {
                int nd0[8];
#pragma unroll
                for (int j = 0; j < 8; ++j) {
                    int ej = lo + j;
                    int ec = (ej < hi) ? ej : lo;
                    nd0[j] = col[ec];
                    cf0[j] = (ej < hi) ? coef[ec] : 0.f;
                }
#pragma unroll
                for (int j = 0; j < 8; ++j) r0[j] = (float)xh[(size_t)nd0[j] * 64 + lane];
            }
#pragma unroll
            for (int j = 0; j < 8; ++j) {
                int ej = lo + 8 + j;
                int ec = (ej < hi) ? ej : lo;
                nd1[j] = col[ec];
                cf1[j] = (ej < hi) ? coef[ec] : 0.f;
            }

            for (int e = lo; e < hi; e += 8) {
                int nd2[8]; float cf2[8];
#pragma unroll
                for (int j = 0; j < 8; ++j) {
                    int ej = e + 16 + j;
                    int ec = (ej < hi) ? ej : lo;
                    nd2[j] = col[ec];
                    cf2[j] = (ej < hi) ? coef[ec] : 0.f;
                }
                float r1[8];
#pragma unroll
                for (int j = 0; j < 8; ++j) r1[j] = (float)xh[(size_t)nd1[j] * 64 + lane];
#pragma unroll
                for (int j = 0; j < 8; ++j) acc = fmaf(r0[j], cf0[j], acc);
#pragma unroll
                for (int j = 0; j < 8; ++j) {
                    r0[j] = r1[j]; cf0[j] = cf1[j];
                    nd1[j] = nd2[j]; cf1[j] = cf2[j];
                }
            }
        }
        aggx[(size_t)i * 64 + lane] = (f16)acc;
    }
}

// ---------------------------------------------------------------- BN + tanh (f16 in, f16 out)
__global__ void k_bn_tanh_h(const f16* __restrict__ h, const float* __restrict__ sums,
                            const float* __restrict__ sumsq, const float* __restrict__ g,
                            const float* __restrict__ be, float Ninv,
                            f16* __restrict__ hh, int n4) {
    int i = blockIdx.x * blockDim.x + threadIdx.x;
    if (i >= n4) return;
    int d = (i & 63) * 4;
    f16x4 v = ((const f16x4*)h)[i];
    f16x4 o;
#pragma unroll
    for (int j = 0; j < 4; ++j) {
        float mu  = sums[d + j] * Ninv;
        float var = sumsq[d + j] * Ninv - mu * mu;
        float s   = g[d + j] * rsqrtf(var + EPS);
        float sh  = be[d + j] - mu * s;
        o[j] = (f16)tanhf(fmaf((float)v[j], s, sh));
    }
    ((f16x4*)hh)[i] = o;
}

// ---------------------------------------------------------------- pooling + output GEMV (f16 h)
__device__ __forceinline__ int lb(const int* __restrict__ a, int n, int v) {
    int lo = 0, hi = n;
    while (lo < hi) {
        int mid = (lo + hi) >> 1;
        if (a[mid] < v) lo = mid + 1; else hi = mid;
    }
    return lo;
}

__global__ void k_pool(const f16* __restrict__ h, const int* __restrict__ batch,
                       const float* __restrict__ Wout, const float* __restrict__ bout,
                       float* __restrict__ out, float* __restrict__ hidden, int N) {
    int g = blockIdx.x;
    int d = threadIdx.x;
    int lo = lb(batch, N, g);
    int hi = lb(batch, N, g + 1);
    float mx = -INFINITY, sm = 0.0f;
    for (int i = lo; i < hi; ++i) {
        float v = (float)h[(size_t)i * D + d];
        mx = fmaxf(mx, v);
        sm += v;
    }
    float mean = sm / (float)(hi - lo);
    hidden[(size_t)g * (2 * D) + d] = mx;
    hidden[(size_t)g * (2 * D) + D + d] = mean;

    float p = mx * Wout[d] + mean * Wout[D + d];
    __shared__ float red[256];
    red[d] = p;
    __syncthreads();
    for (int s = 128; s > 0; s >>= 1) {
        if (d < s) red[d] += red[d + s];
        __syncthreads();
    }
    if (d == 0) out[g] = red[0] + bout[0];
}

// ----------------------------------------------------------------
extern "C" void kernel_launch(void* const* d_in, const int* in_sizes, int n_in,
                              void* d_out, int out_size, void* d_ws, size_t ws_size,
                              hipStream_t stream) {
    const float* x          = (const float*)d_in[0];
    const int*   edge_index = (const int*)d_in[1];
    const int*   batch      = (const int*)d_in[2];
    const float* Wl[4] = {(const float*)d_in[4], (const float*)d_in[6],
                          (const float*)d_in[8], (const float*)d_in[10]};
    const float* gl[4]  = {(const float*)d_in[12], (const float*)d_in[14],
                           (const float*)d_in[16], (const float*)d_in[18]};
    const float* bel[4] = {(const float*)d_in[13], (const float*)d_in[15],
                           (const float*)d_in[17], (const float*)d_in[19]};
    const float* Wout = (const float*)d_in[20];
    const float* bout = (const float*)d_in[21];

    const int N = in_sizes[0] / 64;       // 50000
    const int E = in_sizes[1] / 2;        // 800000
    const int B = out_size / (1 + 2 * D); // 1000

    const int* srcv = edge_index;
    const int* dstv = edge_index + E;

    // workspace carve-up (all f16 activations)
    f16*   hw_h    = (f16*)d_ws;                // [N,D] GEMM out
    f16*   hh      = hw_h + (size_t)N * D;      // [N,D] activations
    f16*   agg_h   = hh + (size_t)N * D;        // [N,D] gather out
    f16*   xh      = agg_h + (size_t)N * D;     // [N,64]
    f16*   aggx    = xh + (size_t)N * 64;       // [N,64]
    f16*   Wt      = aggx + (size_t)N * 64;     // [256,256]
    float* dinv    = (float*)(Wt + 256 * 256);  // [N]
    float* sums    = dinv + N;                  // [D]
    float* sumsq   = sums + D;                  // [D]
    float* coef    = sumsq + D;                 // [E]
    int*   cnt     = (int*)(coef + E);          // [N]
    int*   row_ptr = cnt + N;                   // [N+1]
    int*   cursor  = row_ptr + N + 1;           // [N]
    int*   col     = cursor + N;                // [E]
    int*   partial = col + E;                   // [SCAN_NB]

    float* out_p    = (float*)d_out;            // [B]
    float* hidden_p = out_p + B;                // [B, 512]

    // ---- CSR build
    hipMemsetAsync(cnt, 0, (size_t)N * sizeof(int), stream);
    k_count<<<(E + 255) / 256, 256, 0, stream>>>(dstv, cnt, E);
    const int C = (N + SCAN_NB - 1) / SCAN_NB;
    k_scan_part<<<SCAN_NB, 256, 0, stream>>>(cnt, row_ptr, partial, N, C);
    k_scan_off<<<1, 256, 0, stream>>>(partial);
    k_scan_add<<<(N + 1 + 255) / 256, 256, 0, stream>>>(row_ptr, cursor, partial,
                                                        cnt, dinv, N, C, E);
    k_fill<<<(E + 255) / 256, 256, 0, stream>>>(srcv, dstv, dinv, cursor, col, coef, E);

    // x -> f16
    k_cast<<<(N * 64 / 4 + 255) / 256, 256, 0, stream>>>(x, xh, N * 64 / 4);

    const dim3 gemm_grid((N + 127) / 128, 2);
    const int nd4 = N * D / 4;

    // ---- layer 0: agg(X) [64-dim gather] -> GEMM(+stats) -> BN+tanh
    k_gather64<<<2048, 256, 0, stream>>>(row_ptr, col, coef, xh, dinv, aggx, N);
    k_prep_w<<<64, 256, 0, stream>>>(Wl[0], Wt, 64, sums, sumsq);
    k_gemm<<<gemm_grid, 256, 0, stream>>>(aggx, Wt, hw_h, N, 64, sums, sumsq);
    k_bn_tanh_h<<<(nd4 + 255) / 256, 256, 0, stream>>>(
        hw_h, sums, sumsq, gl[0], bel[0], 1.0f / (float)N, hh, nd4);

    // ---- layers 1-3: GEMM -> gather(+stats) -> BN+tanh
    for (int l = 1; l < 4; ++l) {
        k_prep_w<<<256, 256, 0, stream>>>(Wl[l], Wt, 256, sums, sumsq);
        k_gemm<<<gemm_grid, 256, 0, stream>>>(hh, Wt, hw_h, N, 256, nullptr, nullptr);
        k_gather<<<2048, 256, 0, stream>>>(row_ptr, col, coef, hw_h, dinv,
                                           agg_h, sums, sumsq, N);
        k_bn_tanh_h<<<(nd4 + 255) / 256, 256, 0, stream>>>(
            agg_h, sums, sumsq, gl[l], bel[l], 1.0f / (float)N, hh, nd4);
    }

    k_pool<<<B, 256, 0, stream>>>(hh, batch, Wout, bout, out_p, hidden_p, N);
}

// Round 11
// 772.753 us; speedup vs baseline: 1.0913x; 1.0913x over previous
//
#include <hip/hip_runtime.h>
#include <hip/hip_bf16.h>
#include <math.h>

#define D 256
#define EPS 1e-5f
#define SCAN_NB 256

typedef _Float16 f16;
typedef _Float16 f16x4 __attribute__((ext_vector_type(4)));
typedef _Float16 f16x8 __attribute__((ext_vector_type(8)));
typedef float f32x4v __attribute__((ext_vector_type(4)));

// ---------------------------------------------------------------- CSR build
__global__ void k_count(const int* __restrict__ dst, int* __restrict__ cnt, int E) {
    int e = blockIdx.x * blockDim.x + threadIdx.x;
    if (e < E) atomicAdd(&cnt[dst[e]], 1);
}

__global__ void k_scan_part(const int* __restrict__ cnt, int* __restrict__ row_ptr,
                            int* __restrict__ partial, int N, int C) {
    __shared__ int sdata[256];
    int b = blockIdx.x, t = threadIdx.x;
    int base = b * C;
    int end = base + C; if (end > N) end = N;
    int running = 0;
    for (int ts = base; ts < end; ts += 256) {
        int idx = ts + t;
        int val = (idx < end) ? cnt[idx] : 0;
        sdata[t] = val;
        __syncthreads();
        for (int s = 1; s < 256; s <<= 1) {
            int v = (t >= s) ? sdata[t - s] : 0;
            __syncthreads();
            sdata[t] += v;
            __syncthreads();
        }
        if (idx < end) row_ptr[idx] = running + sdata[t] - val;
        running += sdata[255];
        __syncthreads();
    }
    if (t == 0) partial[b] = running;
}

__global__ void k_scan_off(int* __restrict__ partial) {
    __shared__ int sdata[256];
    int t = threadIdx.x;
    int val = partial[t];
    sdata[t] = val;
    __syncthreads();
    for (int s = 1; s < 256; s <<= 1) {
        int v = (t >= s) ? sdata[t - s] : 0;
        __syncthreads();
        sdata[t] += v;
        __syncthreads();
    }
    partial[t] = sdata[t] - val;
}

__global__ void k_scan_add(int* __restrict__ row_ptr, int* __restrict__ cursor,
                           const int* __restrict__ partial, const int* __restrict__ cnt,
                           float* __restrict__ dinv, int N, int C, int E) {
    int i = blockIdx.x * 256 + threadIdx.x;
    if (i < N) {
        int v = row_ptr[i] + partial[i / C];
        row_ptr[i] = v;
        cursor[i]  = v;
        dinv[i] = rsqrtf(1.0f + (float)cnt[i]);
    }
    if (i == N) row_ptr[N] = E;
}

__global__ void k_fill(const int* __restrict__ src, const int* __restrict__ dst,
                       const float* __restrict__ dinv, int* __restrict__ cursor,
                       int* __restrict__ col, float* __restrict__ coef, int E) {
    int e = blockIdx.x * blockDim.x + threadIdx.x;
    if (e >= E) return;
    int s = src[e], t = dst[e];
    int slot = atomicAdd(&cursor[t], 1);
    col[slot]  = s;
    coef[slot] = dinv[s] * dinv[t];
}

// ---------------------------------------------------------------- casts / weight prep
__global__ void k_cast(const float* __restrict__ in, f16* __restrict__ o, int n4) {
    int i = blockIdx.x * 256 + threadIdx.x;
    if (i >= n4) return;
    float4 v = ((const float4*)in)[i];
    f16x4 h = {(f16)v.x, (f16)v.y, (f16)v.z, (f16)v.w};
    ((f16x4*)o)[i] = h;
}

// Wt[d][k] = (f16) W[k][d]; block 0 zeroes BN-stat accumulators.
__global__ void k_prep_w(const float* __restrict__ W, f16* __restrict__ Wt, int K,
                         float* __restrict__ sums, float* __restrict__ sumsq) {
    int idx = blockIdx.x * 256 + threadIdx.x;
    if (blockIdx.x == 0) {
        sums[threadIdx.x]  = 0.f;
        sumsq[threadIdx.x] = 0.f;
    }
    if (idx >= K * 256) return;
    int k = idx >> 8, d = idx & 255;
    Wt[(size_t)d * K + k] = (f16)W[idx];
}

// ---------------------------------------------------------------- MFMA GEMM (128x128, 2x2 waves, 4x4 MFMA each)
#define KSTEP 32
#define ATS 40
__global__ __launch_bounds__(256)
void k_gemm(const f16* __restrict__ A, const f16* __restrict__ Wt,
            f16* __restrict__ outh, int N, int K,
            float* __restrict__ sums, float* __restrict__ sumsq) {
    __shared__ __align__(16) f16 As[128 * ATS];
    __shared__ __align__(16) f16 Bs[128 * ATS];
    const int r0 = blockIdx.x * 128;
    const int c0 = blockIdx.y * 128;
    const int t = threadIdx.x;
    const int lane = t & 63, wave = t >> 6;
    const int wr = wave >> 1, wc = wave & 1;
    const int quad = lane >> 4, m = lane & 15;

    f32x4v acc[4][4];
#pragma unroll
    for (int i = 0; i < 4; ++i)
#pragma unroll
        for (int j = 0; j < 4; ++j) acc[i][j] = {0.f, 0.f, 0.f, 0.f};

    const int sr = t >> 1;
    const int sc8 = (t & 1) * 16;

    for (int k0 = 0; k0 < K; k0 += KSTEP) {
        int gr = r0 + sr;
        uint4 a0 = make_uint4(0u,0u,0u,0u), a1 = make_uint4(0u,0u,0u,0u);
        if (gr < N) {
            const f16* ap = A + (size_t)gr * K + k0 + sc8;
            a0 = *(const uint4*)ap;
            a1 = *(const uint4*)(ap + 8);
        }
        *(uint4*)(As + sr * ATS + sc8)     = a0;
        *(uint4*)(As + sr * ATS + sc8 + 8) = a1;
        const f16* bp = Wt + (size_t)(c0 + sr) * K + k0 + sc8;
        *(uint4*)(Bs + sr * ATS + sc8)     = *(const uint4*)bp;
        *(uint4*)(Bs + sr * ATS + sc8 + 8) = *(const uint4*)(bp + 8);
        __syncthreads();

        f16x8 af[4], bf[4];
#pragma unroll
        for (int i = 0; i < 4; ++i)
            af[i] = *(const f16x8*)(As + (wr * 64 + i * 16 + m) * ATS + quad * 8);
#pragma unroll
        for (int j = 0; j < 4; ++j)
            bf[j] = *(const f16x8*)(Bs + (wc * 64 + j * 16 + m) * ATS + quad * 8);
#pragma unroll
        for (int i = 0; i < 4; ++i)
#pragma unroll
            for (int j = 0; j < 4; ++j)
                acc[i][j] = __builtin_amdgcn_mfma_f32_16x16x32_f16(af[i], bf[j], acc[i][j], 0, 0, 0);
        __syncthreads();
    }

#pragma unroll
    for (int i = 0; i < 4; ++i) {
#pragma unroll
        for (int r = 0; r < 4; ++r) {
            int row = r0 + wr * 64 + i * 16 + quad * 4 + r;
            if (row < N) {
#pragma unroll
                for (int j = 0; j < 4; ++j) {
                    int colm = c0 + wc * 64 + j * 16 + m;
                    outh[(size_t)row * D + colm] = (f16)acc[i][j][r];
                }
            }
        }
    }

    if (sums) {
        __shared__ float cs[128], css[128];
        if (t < 128) { cs[t] = 0.f; css[t] = 0.f; }
        __syncthreads();
#pragma unroll
        for (int j = 0; j < 4; ++j) {
            int f = wc * 64 + j * 16 + m;
            float s = 0.f, q = 0.f;
#pragma unroll
            for (int i = 0; i < 4; ++i)
#pragma unroll
                for (int r = 0; r < 4; ++r) {
                    float v = acc[i][j][r];
                    s += v; q += v * v;
                }
            atomicAdd(&cs[f], s);
            atomicAdd(&css[f], q);
        }
        __syncthreads();
        if (t < 128) {
            atomicAdd(&sums[c0 + t], cs[t]);
            atomicAdd(&sumsq[c0 + t], css[t]);
        }
    }
}

// ---------------------------------------------------------------- gather, 256-dim rows (layers 1-3)
// DUAL-node per wave: two independent edge streams -> 16 row loads in flight/chunk.
__global__ __launch_bounds__(256)
void k_gather(const int* __restrict__ row_ptr, const int* __restrict__ col,
              const float* __restrict__ coef, const f16* __restrict__ hw,
              const float* __restrict__ dinv,
              f16* __restrict__ out, float* __restrict__ sums,
              float* __restrict__ sumsq, int N) {
    const int lane = threadIdx.x & 63;
    const int wave = threadIdx.x >> 6;
    const f16x4* __restrict__ hw4 = (const f16x4*)hw;
    f16x4* __restrict__ out4 = (f16x4*)out;

    float4 s4  = make_float4(0.f, 0.f, 0.f, 0.f);
    float4 ss4 = make_float4(0.f, 0.f, 0.f, 0.f);

    int wslot  = blockIdx.x * 4 + wave;
    int wtotal = gridDim.x * 4;
    for (int i1 = wslot; i1 < N; i1 += 2 * wtotal) {
        int i2 = i1 + wtotal;
        bool has2 = i2 < N;
        int lo1 = row_ptr[i1], hi1 = row_ptr[i1 + 1];
        int lo2 = 0, hi2 = 0;
        if (has2) { lo2 = row_ptr[i2]; hi2 = row_ptr[i2 + 1]; }
        float dd1 = dinv[i1]; dd1 *= dd1;
        float dd2 = has2 ? dinv[i2] : 0.f; dd2 *= dd2;
        f16x4 hv1 = hw4[(size_t)i1 * 64 + lane];
        f16x4 hv2 = has2 ? hw4[(size_t)i2 * 64 + lane] : (f16x4){0,0,0,0};
        float4 a1, a2;
        a1.x = (float)hv1[0]*dd1; a1.y = (float)hv1[1]*dd1;
        a1.z = (float)hv1[2]*dd1; a1.w = (float)hv1[3]*dd1;
        a2.x = (float)hv2[0]*dd2; a2.y = (float)hv2[1]*dd2;
        a2.z = (float)hv2[2]*dd2; a2.w = (float)hv2[3]*dd2;

        int e1 = lo1, e2 = lo2;
        while (e1 < hi1 || e2 < hi2) {
            int n1[8], n2[8]; float c1[8], c2[8];
#pragma unroll
            for (int j = 0; j < 8; ++j) {
                int ej = e1 + j;
                int ec = (ej < hi1) ? ej : lo1;
                n1[j] = col[ec];
                c1[j] = (ej < hi1) ? coef[ec] : 0.f;
            }
#pragma unroll
            for (int j = 0; j < 8; ++j) {
                int ej = e2 + j;
                int ec = (ej < hi2) ? ej : lo2;
                n2[j] = col[ec];
                c2[j] = (ej < hi2) ? coef[ec] : 0.f;
            }
            f16x4 r1[8], r2[8];
#pragma unroll
            for (int j = 0; j < 8; ++j) r1[j] = hw4[(size_t)n1[j] * 64 + lane];
#pragma unroll
            for (int j = 0; j < 8; ++j) r2[j] = hw4[(size_t)n2[j] * 64 + lane];
#pragma unroll
            for (int j = 0; j < 8; ++j) {
                a1.x = fmaf((float)r1[j][0], c1[j], a1.x);
                a1.y = fmaf((float)r1[j][1], c1[j], a1.y);
                a1.z = fmaf((float)r1[j][2], c1[j], a1.z);
                a1.w = fmaf((float)r1[j][3], c1[j], a1.w);
                a2.x = fmaf((float)r2[j][0], c2[j], a2.x);
                a2.y = fmaf((float)r2[j][1], c2[j], a2.y);
                a2.z = fmaf((float)r2[j][2], c2[j], a2.z);
                a2.w = fmaf((float)r2[j][3], c2[j], a2.w);
            }
            e1 += 8; e2 += 8;
        }

        f16x4 o1 = {(f16)a1.x, (f16)a1.y, (f16)a1.z, (f16)a1.w};
        out4[(size_t)i1 * 64 + lane] = o1;
        s4.x += a1.x; s4.y += a1.y; s4.z += a1.z; s4.w += a1.w;
        ss4.x += a1.x*a1.x; ss4.y += a1.y*a1.y; ss4.z += a1.z*a1.z; ss4.w += a1.w*a1.w;
        if (has2) {
            f16x4 o2 = {(f16)a2.x, (f16)a2.y, (f16)a2.z, (f16)a2.w};
            out4[(size_t)i2 * 64 + lane] = o2;
            s4.x += a2.x; s4.y += a2.y; s4.z += a2.z; s4.w += a2.w;
            ss4.x += a2.x*a2.x; ss4.y += a2.y*a2.y; ss4.z += a2.z*a2.z; ss4.w += a2.w*a2.w;
        }
    }

    __shared__ float rs[4][256];
    __shared__ float rss[4][256];
    int f = lane * 4;
    rs[wave][f + 0] = s4.x;  rs[wave][f + 1] = s4.y;
    rs[wave][f + 2] = s4.z;  rs[wave][f + 3] = s4.w;
    rss[wave][f + 0] = ss4.x; rss[wave][f + 1] = ss4.y;
    rss[wave][f + 2] = ss4.z; rss[wave][f + 3] = ss4.w;
    __syncthreads();
    int t = threadIdx.x;
    float rsum  = rs[0][t] + rs[1][t] + rs[2][t] + rs[3][t];
    float rsum2 = rss[0][t] + rss[1][t] + rss[2][t] + rss[3][t];
    atomicAdd(&sums[t], rsum);
    atomicAdd(&sumsq[t], rsum2);
}

// ---------------------------------------------------------------- gather64: QUAD-node per wave
// lane = 16q+m: 16-lane group q owns node i0+q, lane holds f16x4 (64 feats / 16 lanes).
// One wave row-load = 4 x 128B rows = 512B fully coalesced.
__global__ __launch_bounds__(256)
void k_gather64(const int* __restrict__ row_ptr, const int* __restrict__ col,
                const float* __restrict__ coef, const f16* __restrict__ xh,
                const float* __restrict__ dinv, f16* __restrict__ aggx, int N) {
    const int lane = threadIdx.x & 63;
    const int wave = threadIdx.x >> 6;
    const int q = lane >> 4, m = lane & 15;
    const f16x4* __restrict__ x4 = (const f16x4*)xh;   // row i slice m = x4[i*16+m]
    f16x4* __restrict__ o4 = (f16x4*)aggx;

    int slot   = blockIdx.x * 4 + wave;
    int stride = gridDim.x * 4;
    for (int i0 = slot * 4; i0 < N; i0 += stride * 4) {
        int i = i0 + q;
        bool act = i < N;
        int lo = act ? row_ptr[i] : 0;
        int hi = act ? row_ptr[i + 1] : 0;
        float dd = act ? dinv[i] : 0.f; dd *= dd;
        f16x4 hv = act ? x4[(size_t)i * 16 + m] : (f16x4){0,0,0,0};
        float4 acc;
        acc.x = (float)hv[0]*dd; acc.y = (float)hv[1]*dd;
        acc.z = (float)hv[2]*dd; acc.w = (float)hv[3]*dd;

        for (int e = lo; e < hi; e += 8) {
            int nd[8]; float cf[8];
#pragma unroll
            for (int j = 0; j < 8; ++j) {
                int ej = e + j;
                int ec = (ej < hi) ? ej : lo;
                nd[j] = col[ec];
                cf[j] = (ej < hi) ? coef[ec] : 0.f;
            }
            f16x4 r[8];
#pragma unroll
            for (int j = 0; j < 8; ++j) r[j] = x4[(size_t)nd[j] * 16 + m];
#pragma unroll
            for (int j = 0; j < 8; ++j) {
                acc.x = fmaf((float)r[j][0], cf[j], acc.x);
                acc.y = fmaf((float)r[j][1], cf[j], acc.y);
                acc.z = fmaf((float)r[j][2], cf[j], acc.z);
                acc.w = fmaf((float)r[j][3], cf[j], acc.w);
            }
        }
        if (act) {
            f16x4 o = {(f16)acc.x, (f16)acc.y, (f16)acc.z, (f16)acc.w};
            o4[(size_t)i * 16 + m] = o;
        }
    }
}

// ---------------------------------------------------------------- BN + tanh (f16 in, f16 out)
__global__ void k_bn_tanh_h(const f16* __restrict__ h, const float* __restrict__ sums,
                            const float* __restrict__ sumsq, const float* __restrict__ g,
                            const float* __restrict__ be, float Ninv,
                            f16* __restrict__ hh, int n4) {
    int i = blockIdx.x * blockDim.x + threadIdx.x;
    if (i >= n4) return;
    int d = (i & 63) * 4;
    f16x4 v = ((const f16x4*)h)[i];
    f16x4 o;
#pragma unroll
    for (int j = 0; j < 4; ++j) {
        float mu  = sums[d + j] * Ninv;
        float var = sumsq[d + j] * Ninv - mu * mu;
        float s   = g[d + j] * rsqrtf(var + EPS);
        float sh  = be[d + j] - mu * s;
        o[j] = (f16)tanhf(fmaf((float)v[j], s, sh));
    }
    ((f16x4*)hh)[i] = o;
}

// ---------------------------------------------------------------- pool with fused last-layer BN + tanh
__device__ __forceinline__ int lb(const int* __restrict__ a, int n, int v) {
    int lo = 0, hi = n;
    while (lo < hi) {
        int mid = (lo + hi) >> 1;
        if (a[mid] < v) lo = mid + 1; else hi = mid;
    }
    return lo;
}

__global__ void k_pool(const f16* __restrict__ agg, const float* __restrict__ sums,
                       const float* __restrict__ sumsq, const float* __restrict__ gg,
                       const float* __restrict__ be, float Ninv,
                       const int* __restrict__ batch,
                       const float* __restrict__ Wout, const float* __restrict__ bout,
                       float* __restrict__ out, float* __restrict__ hidden, int N) {
    int g = blockIdx.x;
    int d = threadIdx.x;
    float mu  = sums[d] * Ninv;
    float var = sumsq[d] * Ninv - mu * mu;
    float sc  = gg[d] * rsqrtf(var + EPS);
    float sh  = be[d] - mu * sc;

    int lo = lb(batch, N, g);
    int hi = lb(batch, N, g + 1);
    float mx = -INFINITY, sm = 0.0f;
    for (int i = lo; i < hi; ++i) {
        float v = tanhf(fmaf((float)agg[(size_t)i * D + d], sc, sh));
        mx = fmaxf(mx, v);
        sm += v;
    }
    float mean = sm / (float)(hi - lo);
    hidden[(size_t)g * (2 * D) + d] = mx;
    hidden[(size_t)g * (2 * D) + D + d] = mean;

    float p = mx * Wout[d] + mean * Wout[D + d];
    __shared__ float red[256];
    red[d] = p;
    __syncthreads();
    for (int s = 128; s > 0; s >>= 1) {
        if (d < s) red[d] += red[d + s];
        __syncthreads();
    }
    if (d == 0) out[g] = red[0] + bout[0];
}

// ----------------------------------------------------------------
extern "C" void kernel_launch(void* const* d_in, const int* in_sizes, int n_in,
                              void* d_out, int out_size, void* d_ws, size_t ws_size,
                              hipStream_t stream) {
    const float* x          = (const float*)d_in[0];
    const int*   edge_index = (const int*)d_in[1];
    const int*   batch      = (const int*)d_in[2];
    const float* Wl[4] = {(const float*)d_in[4], (const float*)d_in[6],
                          (const float*)d_in[8], (const float*)d_in[10]};
    const float* gl[4]  = {(const float*)d_in[12], (const float*)d_in[14],
                           (const float*)d_in[16], (const float*)d_in[18]};
    const float* bel[4] = {(const float*)d_in[13], (const float*)d_in[15],
                           (const float*)d_in[17], (const float*)d_in[19]};
    const float* Wout = (const float*)d_in[20];
    const float* bout = (const float*)d_in[21];

    const int N = in_sizes[0] / 64;       // 50000
    const int E = in_sizes[1] / 2;        // 800000
    const int B = out_size / (1 + 2 * D); // 1000

    const int* srcv = edge_index;
    const int* dstv = edge_index + E;

    // workspace carve-up
    f16*   hw_h    = (f16*)d_ws;                // [N,D] GEMM out
    f16*   hh      = hw_h + (size_t)N * D;      // [N,D] activations
    f16*   agg_h   = hh + (size_t)N * D;        // [N,D] gather out
    f16*   xh      = agg_h + (size_t)N * D;     // [N,64]
    f16*   aggx    = xh + (size_t)N * 64;       // [N,64]
    f16*   Wt      = aggx + (size_t)N * 64;     // [256,256]
    float* dinv    = (float*)(Wt + 256 * 256);  // [N]
    float* sums    = dinv + N;                  // [D]
    float* sumsq   = sums + D;                  // [D]
    float* coef    = sumsq + D;                 // [E]
    int*   cnt     = (int*)(coef + E);          // [N]
    int*   row_ptr = cnt + N;                   // [N+1]
    int*   cursor  = row_ptr + N + 1;           // [N]
    int*   col     = cursor + N;                // [E]
    int*   partial = col + E;                   // [SCAN_NB]

    float* out_p    = (float*)d_out;            // [B]
    float* hidden_p = out_p + B;                // [B, 512]

    // ---- CSR build
    hipMemsetAsync(cnt, 0, (size_t)N * sizeof(int), stream);
    k_count<<<(E + 255) / 256, 256, 0, stream>>>(dstv, cnt, E);
    const int C = (N + SCAN_NB - 1) / SCAN_NB;
    k_scan_part<<<SCAN_NB, 256, 0, stream>>>(cnt, row_ptr, partial, N, C);
    k_scan_off<<<1, 256, 0, stream>>>(partial);
    k_scan_add<<<(N + 1 + 255) / 256, 256, 0, stream>>>(row_ptr, cursor, partial,
                                                        cnt, dinv, N, C, E);
    k_fill<<<(E + 255) / 256, 256, 0, stream>>>(srcv, dstv, dinv, cursor, col, coef, E);

    // x -> f16
    k_cast<<<(N * 64 / 4 + 255) / 256, 256, 0, stream>>>(x, xh, N * 64 / 4);

    const dim3 gemm_grid((N + 127) / 128, 2);
    const int nd4 = N * D / 4;

    // ---- layer 0: agg(X) quad-gather -> GEMM(+stats) -> BN+tanh
    k_gather64<<<2048, 256, 0, stream>>>(row_ptr, col, coef, xh, dinv, aggx, N);
    k_prep_w<<<64, 256, 0, stream>>>(Wl[0], Wt, 64, sums, sumsq);
    k_gemm<<<gemm_grid, 256, 0, stream>>>(aggx, Wt, hw_h, N, 64, sums, sumsq);
    k_bn_tanh_h<<<(nd4 + 255) / 256, 256, 0, stream>>>(
        hw_h, sums, sumsq, gl[0], bel[0], 1.0f / (float)N, hh, nd4);

    // ---- layers 1-3: GEMM -> dual-gather(+stats) -> BN+tanh (layer 3's BN fused into pool)
    for (int l = 1; l < 4; ++l) {
        k_prep_w<<<256, 256, 0, stream>>>(Wl[l], Wt, 256, sums, sumsq);
        k_gemm<<<gemm_grid, 256, 0, stream>>>(hh, Wt, hw_h, N, 256, nullptr, nullptr);
        k_gather<<<2048, 256, 0, stream>>>(row_ptr, col, coef, hw_h, dinv,
                                           agg_h, sums, sumsq, N);
        if (l < 3) {
            k_bn_tanh_h<<<(nd4 + 255) / 256, 256, 0, stream>>>(
                agg_h, sums, sumsq, gl[l], bel[l], 1.0f / (float)N, hh, nd4);
        }
    }

    k_pool<<<B, 256, 0, stream>>>(agg_h, sums, sumsq, gl[3], bel[3], 1.0f / (float)N,
                                  batch, Wout, bout, out_p, hidden_p, N);
}